// Round 9
// baseline (330.397 us; speedup 1.0000x reference)
//
#include <hip/hip_runtime.h>
#include <hip/hip_bf16.h>
#include <math.h>

#define S_LEN 4096
#define EMB   1024
#define NHEAD 16
#define HDIM  64

typedef __attribute__((ext_vector_type(8))) _Float16 half8;
typedef __attribute__((ext_vector_type(4))) _Float16 half4;
typedef __attribute__((ext_vector_type(4))) float float4_t;

#define GLOBAL_AS(p) ((const __attribute__((address_space(1))) void*)(p))
#define LDS_AS(p)    ((__attribute__((address_space(3))) void*)(p))

#define LOG2E 1.4426950408889634f

// ---------------------------------------------------------------------------
// fused prep: blocks [0,4096) convert x fp32->fp16; [4096,4864) transpose
// Wqkv [1024,3072] -> WTh [3072,1024]; [4864,5120) transpose Wp -> WpT.
// ---------------------------------------------------------------------------
__global__ __launch_bounds__(256) void prep(
    const float* __restrict__ x, const float* __restrict__ Wqkv,
    const float* __restrict__ Wp,
    _Float16* __restrict__ xh, _Float16* __restrict__ WTh,
    _Float16* __restrict__ WpT)
{
    const int bid = blockIdx.x;
    if (bid < 4096) {
        const int i = bid * 256 + threadIdx.x;
        const float4_t v = ((const float4_t*)x)[i];
        half4 hh;
#pragma unroll
        for (int j = 0; j < 4; ++j) hh[j] = (_Float16)v[j];
        ((half4*)xh)[i] = hh;
        return;
    }
    __shared__ float t[64][65];
    const float* in;
    _Float16* out;
    int R, C, bx, by;
    if (bid < 4096 + 768) {
        const int idx = bid - 4096;
        bx = idx % 48; by = idx / 48;     // C=3072 -> 48 col-tiles, R=1024 -> 16
        in = Wqkv; out = WTh; R = 1024; C = 3072;
    } else {
        const int idx = bid - 4864;
        bx = idx & 15; by = idx >> 4;
        in = Wp; out = WpT; R = 1024; C = 1024;
    }
    const int r0 = by * 64, c0 = bx * 64;
    for (int i = threadIdx.x; i < 64 * 64; i += 256) {
        int r = i >> 6, c = i & 63;
        t[r][c] = in[(size_t)(r0 + r) * C + c0 + c];
    }
    __syncthreads();
    for (int i = threadIdx.x; i < 64 * 64; i += 256) {
        int c = i >> 6, r = i & 63;
        out[(size_t)(c0 + c) * R + r0 + r] = (_Float16)t[r][c];
    }
}

// ---------------------------------------------------------------------------
// QKV GEMM, plain fp16, m97 structure: 128x128 tile, BK=32, global_load_lds.
// Epilogue: cols<1024 -> q plane; 1024..2047 -> k plane SCALED by log2(e);
// cols>=2048 -> fp16 V^T [1024,4096], packed half4 along s (r-contiguous).
// ---------------------------------------------------------------------------
__global__ __launch_bounds__(256) void gemm_qkv(
    const _Float16* __restrict__ Ag, const _Float16* __restrict__ Bg,
    const float* __restrict__ bias,
    _Float16* __restrict__ qk, _Float16* __restrict__ vt, int K)
{
    constexpr int BK = 32;
    __shared__ _Float16 Ah[128 * BK];
    __shared__ _Float16 Bh[128 * BK];

    const int tid = threadIdx.x;
    const int wave = tid >> 6, lane = tid & 63;
    const int l16 = lane & 15, quad = lane >> 4;
    const int wr = wave >> 1, wc = wave & 1;
    const int row0 = blockIdx.y * 128, col0 = blockIdx.x * 128;
    const int lrow = lane >> 2, lc8 = (lane & 3) * 8;

    float4_t acc[4][4];
#pragma unroll
    for (int i = 0; i < 4; ++i)
#pragma unroll
        for (int j = 0; j < 4; ++j) acc[i][j] = (float4_t){0.f, 0.f, 0.f, 0.f};

    for (int k0 = 0; k0 < K; k0 += BK) {
        __syncthreads();
#pragma unroll
        for (int i = 0; i < 2; ++i) {
            const int ar = i * 64 + wave * 16;
            __builtin_amdgcn_global_load_lds(
                GLOBAL_AS(Ag + (size_t)(row0 + ar + lrow) * K + k0 + lc8),
                LDS_AS(&Ah[ar * BK]), 16, 0, 0);
            __builtin_amdgcn_global_load_lds(
                GLOBAL_AS(Bg + (size_t)(col0 + ar + lrow) * K + k0 + lc8),
                LDS_AS(&Bh[ar * BK]), 16, 0, 0);
        }
        __syncthreads();

        half8 af[4], bfr[4];
#pragma unroll
        for (int t = 0; t < 4; ++t) {
            af[t]  = *(const half8*)&Ah[(wr * 64 + t * 16 + l16) * BK + quad * 8];
            bfr[t] = *(const half8*)&Bh[(wc * 64 + t * 16 + l16) * BK + quad * 8];
        }
#pragma unroll
        for (int i = 0; i < 4; ++i)
#pragma unroll
            for (int j = 0; j < 4; ++j)
                acc[i][j] = __builtin_amdgcn_mfma_f32_16x16x32_f16(af[i], bfr[j], acc[i][j], 0, 0, 0);
    }

#pragma unroll
    for (int i = 0; i < 4; ++i) {
#pragma unroll
        for (int j = 0; j < 4; ++j) {
            const int colb = col0 + wc * 64 + j * 16 + l16;
            const float bv = bias[colb];
            const int rowb = row0 + wr * 64 + i * 16 + quad * 4;
            if (colb < 2048) {
                const float sc = (colb >= 1024) ? LOG2E : 1.0f;
#pragma unroll
                for (int r = 0; r < 4; ++r)
                    qk[(size_t)(rowb + r) * 2048 + colb] =
                        (_Float16)((acc[i][j][r] + bv) * sc);
            } else {
                half4 w;
#pragma unroll
                for (int r = 0; r < 4; ++r) w[r] = (_Float16)(acc[i][j][r] + bv);
                *(half4*)&vt[(size_t)(colb - 2048) * 4096 + rowb] = w;
            }
        }
    }
}

// ---------------------------------------------------------------------------
// Out-projection GEMM, plain fp16. A [M,K] fp16 (res), B^T [N,K] fp16 (Wp^T).
// ---------------------------------------------------------------------------
__global__ __launch_bounds__(256) void gemm_out(
    const _Float16* __restrict__ Ag, const _Float16* __restrict__ Bg,
    const float* __restrict__ bias, float* __restrict__ C, int N, int K)
{
    constexpr int BK = 32;
    __shared__ _Float16 Ah[128 * BK];
    __shared__ _Float16 Bh[128 * BK];

    const int tid = threadIdx.x;
    const int wave = tid >> 6, lane = tid & 63;
    const int l16 = lane & 15, quad = lane >> 4;
    const int wr = wave >> 1, wc = wave & 1;
    const int row0 = blockIdx.y * 128, col0 = blockIdx.x * 128;
    const int lrow = lane >> 2, lc8 = (lane & 3) * 8;

    float4_t acc[4][4];
#pragma unroll
    for (int i = 0; i < 4; ++i)
#pragma unroll
        for (int j = 0; j < 4; ++j) acc[i][j] = (float4_t){0.f, 0.f, 0.f, 0.f};

    for (int k0 = 0; k0 < K; k0 += BK) {
        __syncthreads();
#pragma unroll
        for (int i = 0; i < 2; ++i) {
            const int ar = i * 64 + wave * 16;
            __builtin_amdgcn_global_load_lds(
                GLOBAL_AS(Ag + (size_t)(row0 + ar + lrow) * K + k0 + lc8),
                LDS_AS(&Ah[ar * BK]), 16, 0, 0);
            __builtin_amdgcn_global_load_lds(
                GLOBAL_AS(Bg + (size_t)(col0 + ar + lrow) * K + k0 + lc8),
                LDS_AS(&Bh[ar * BK]), 16, 0, 0);
        }
        __syncthreads();

        half8 af[4], bfr[4];
#pragma unroll
        for (int t = 0; t < 4; ++t) {
            af[t]  = *(const half8*)&Ah[(wr * 64 + t * 16 + l16) * BK + quad * 8];
            bfr[t] = *(const half8*)&Bh[(wc * 64 + t * 16 + l16) * BK + quad * 8];
        }
#pragma unroll
        for (int i = 0; i < 4; ++i)
#pragma unroll
            for (int j = 0; j < 4; ++j)
                acc[i][j] = __builtin_amdgcn_mfma_f32_16x16x32_f16(af[i], bfr[j], acc[i][j], 0, 0, 0);
    }

#pragma unroll
    for (int i = 0; i < 4; ++i) {
#pragma unroll
        for (int j = 0; j < 4; ++j) {
            const int colb = col0 + wc * 64 + j * 16 + l16;
            const float bv = bias[colb];
#pragma unroll
            for (int r = 0; r < 4; ++r) {
                const int row = row0 + wr * 64 + i * 16 + quad * 4 + r;
                C[(size_t)row * N + colb] = acc[i][j][r] + bv;
            }
        }
    }
}

// ---------------------------------------------------------------------------
// MFMA causal flash attention — barrier-free independent-wave version.
// 1024 blocks x 128 threads = 2048 waves; the two waves of a block share
// NOTHING (no __syncthreads anywhere). Each wave owns a 16-row q-tile pair
// {pw, 255-pw} of one head (256 tiles/head) -> uniform 65 k-iterations.
//   xcd  = bid & 7, head = xcd*2 + ((bid>>3)&1)  (XCD-pinned K/V in L2)
//   pw   = (bid >> 4) * 2 + wave                 (0..127 per head)
// Per k-iter the wave stages its own 64-key K-tile into a private LDS region
// (register-prefetched; same-wave DS ordering needs no barrier) and reads
// V^T fragments straight from global (L2-resident, 16 rows x 64 B/load).
// S^T = K Q^T formulation (round 8): per-lane softmax + 2 shuffles; P
// relayout via per-wave Pb (4x b64 write, 2x b128 read). DS ops/iter: 22.
// ---------------------------------------------------------------------------
__global__ __launch_bounds__(128, 2) void flash_attn_f16(
    const _Float16* __restrict__ qk, const _Float16* __restrict__ v_t,
    _Float16* __restrict__ resh)
{
    __shared__ __align__(16) _Float16 Ks[2][64][72];   // per-wave K tile
    __shared__ __align__(16) _Float16 Pb[2][16][72];   // per-wave P [q][key]

    const int bid  = blockIdx.x;
    const int h    = (bid & 7) * 2 + ((bid >> 3) & 1);
    const int wave = threadIdx.x >> 6;
    const int lane = threadIdx.x & 63;
    const int l16  = lane & 15;
    const int quad = lane >> 4;
    const int pw   = (bid >> 4) * 2 + wave;   // 0..127
    const int srow = lane >> 3;               // 0..7
    const int sc8  = (lane & 7) * 8;          // 0..56

    const _Float16* kplane = qk + 1024 + h * HDIM;
    const _Float16* vplane = v_t + (size_t)h * HDIM * 4096;

    for (int half = 0; half < 2; ++half) {
        const int tile = half ? 255 - pw : pw;
        const int q0   = tile * 16;
        const int kb_last = (tile >> 2) * 64;

        // ---- Q fragment (B-operand) ---------------------------------------
        const size_t qoff = (size_t)(q0 + l16) * 2048 + h * HDIM + quad * 8;
        half8 qf0 = *(const half8*)(qk + qoff);
        half8 qf1 = *(const half8*)(qk + qoff + 32);

        float4_t o[4];
#pragma unroll
        for (int c = 0; c < 4; ++c) o[c] = (float4_t){0.f, 0.f, 0.f, 0.f};
        float m_r = -INFINITY, l_r = 0.f;

        // ---- register prefetch of K tile kb=0 (8 rows/thread-slot) --------
        half8 pf_k[8];
#pragma unroll
        for (int p = 0; p < 8; ++p)
            pf_k[p] = *(const half8*)(kplane + (size_t)(srow + p * 8) * 2048 + sc8);

        for (int kb = 0; kb <= kb_last; kb += 64) {
            // ---- stage K into this wave's private LDS region --------------
#pragma unroll
            for (int p = 0; p < 8; ++p)
                *(half8*)&Ks[wave][srow + p * 8][sc8] = pf_k[p];

            if (kb < kb_last) {   // prefetch next K tile (overlaps compute)
                const int kn = kb + 64;
#pragma unroll
                for (int p = 0; p < 8; ++p)
                    pf_k[p] = *(const half8*)(kplane + (size_t)(kn + srow + p * 8) * 2048 + sc8);
            }

            // ---- V^T fragments straight from global (L2) ------------------
            half8 va0[4], va1[4];
#pragma unroll
            for (int ct = 0; ct < 4; ++ct) {
                const _Float16* vp = vplane + (size_t)(ct * 16 + l16) * 4096 + kb + quad * 8;
                va0[ct] = *(const half8*)(vp);
                va1[ct] = *(const half8*)(vp + 32);
            }

            // ---- S^T = K Q^T (log2-domain logits) -------------------------
            float4_t s[4];
#pragma unroll
            for (int t = 0; t < 4; ++t) {
                half8 a0 = *(const half8*)&Ks[wave][t * 16 + l16][quad * 8];
                half8 a1 = *(const half8*)&Ks[wave][t * 16 + l16][32 + quad * 8];
                float4_t a = (float4_t){0.f, 0.f, 0.f, 0.f};
                a = __builtin_amdgcn_mfma_f32_16x16x32_f16(a0, qf0, a, 0, 0, 0);
                a = __builtin_amdgcn_mfma_f32_16x16x32_f16(a1, qf1, a, 0, 0, 0);
                s[t] = a;
            }

            // ---- causal mask (diagonal-straddling tile only) --------------
            if (kb + 63 > q0) {
                const int qg = q0 + l16;
#pragma unroll
                for (int t = 0; t < 4; ++t)
#pragma unroll
                    for (int r = 0; r < 4; ++r) {
                        const int key = kb + t * 16 + quad * 4 + r;
                        if (key > qg) s[t][r] = -INFINITY;
                    }
            }

            // ---- online softmax: per-lane local + 2 cross-quad shuffles ---
            float mx = s[0][0];
#pragma unroll
            for (int t = 0; t < 4; ++t)
#pragma unroll
                for (int r = 0; r < 4; ++r) mx = fmaxf(mx, s[t][r]);
            mx = fmaxf(mx, __shfl_xor(mx, 16));
            mx = fmaxf(mx, __shfl_xor(mx, 32));
            const float mnew  = fmaxf(m_r, mx);
            const float alpha = __builtin_amdgcn_exp2f(m_r - mnew);

            float p[4][4];
            float sum = 0.f;
#pragma unroll
            for (int t = 0; t < 4; ++t)
#pragma unroll
                for (int r = 0; r < 4; ++r) {
                    p[t][r] = __builtin_amdgcn_exp2f(s[t][r] - mnew);
                    sum += p[t][r];
                }
            sum += __shfl_xor(sum, 16);
            sum += __shfl_xor(sum, 32);
            l_r = l_r * alpha + sum;
            m_r = mnew;
#pragma unroll
            for (int ct = 0; ct < 4; ++ct)
#pragma unroll
                for (int r = 0; r < 4; ++r) o[ct][r] *= alpha;

            // ---- P store (4 keys contiguous) + read-back as B-operand -----
#pragma unroll
            for (int t = 0; t < 4; ++t) {
                half4 w;
#pragma unroll
                for (int r = 0; r < 4; ++r) w[r] = (_Float16)p[t][r];
                *(half4*)&Pb[wave][l16][t * 16 + quad * 4] = w;
            }
            half8 pb0 = *(const half8*)&Pb[wave][l16][quad * 8];
            half8 pb1 = *(const half8*)&Pb[wave][l16][32 + quad * 8];

            // ---- O^T += V^T P^T -------------------------------------------
#pragma unroll
            for (int ct = 0; ct < 4; ++ct) {
                o[ct] = __builtin_amdgcn_mfma_f32_16x16x32_f16(va0[ct], pb0, o[ct], 0, 0, 0);
                o[ct] = __builtin_amdgcn_mfma_f32_16x16x32_f16(va1[ct], pb1, o[ct], 0, 0, 0);
            }
        } // kb

        // ---- epilogue: O^T[d][q] / l -> resh[q][d], half4 packed ----------
        const float inv = 1.0f / l_r;
#pragma unroll
        for (int ct = 0; ct < 4; ++ct) {
            half4 w;
#pragma unroll
            for (int r = 0; r < 4; ++r) w[r] = (_Float16)(o[ct][r] * inv);
            *(half4*)&resh[(size_t)(q0 + l16) * EMB + h * HDIM + ct * 16 + quad * 4] = w;
        }
    } // half
}

// ---------------------------------------------------------------------------
// launch
// ---------------------------------------------------------------------------
extern "C" void kernel_launch(void* const* d_in, const int* in_sizes, int n_in,
                              void* d_out, int out_size, void* d_ws, size_t ws_size,
                              hipStream_t stream)
{
    const float* x    = (const float*)d_in[0];
    const float* Wqkv = (const float*)d_in[2];
    const float* bqkv = (const float*)d_in[3];
    const float* Wp   = (const float*)d_in[4];
    const float* bp   = (const float*)d_in[5];
    float* out = (float*)d_out;

    _Float16* xh  = (_Float16*)d_ws;                 // [4096,1024] fp16
    _Float16* WTh = xh + (size_t)4096 * 1024;        // [3072,1024] fp16
    _Float16* qkh = WTh + (size_t)3072 * 1024;       // [4096,2048] fp16
    _Float16* vtg = qkh + (size_t)4096 * 2048;       // V^T [1024,4096] fp16
    _Float16* WpT = vtg + (size_t)1024 * 4096;       // [1024,1024] fp16
    _Float16* resh = xh;            // alias: x fp16 dead after QKV GEMM

    dim3 blk(256);

    prep<<<dim3(5120), blk, 0, stream>>>(x, Wqkv, Wp, xh, WTh, WpT);

    gemm_qkv<<<dim3(3072 / 128, 4096 / 128), blk, 0, stream>>>(
        xh, WTh, bqkv, qkh, vtg, 1024);

    flash_attn_f16<<<dim3(1024), dim3(128), 0, stream>>>(qkh, vtg, resh);

    gemm_out<<<dim3(1024 / 128, 4096 / 128), blk, 0, stream>>>(
        resh, WpT, bp, out, 1024, 1024);
}

// Round 10
// 266.844 us; speedup vs baseline: 1.2382x; 1.2382x over previous
//
#include <hip/hip_runtime.h>
#include <hip/hip_bf16.h>
#include <math.h>

#define S_LEN 4096
#define EMB   1024
#define NHEAD 16
#define HDIM  64

typedef __attribute__((ext_vector_type(8))) _Float16 half8;
typedef __attribute__((ext_vector_type(4))) _Float16 half4;
typedef __attribute__((ext_vector_type(4))) float float4_t;

#define GLOBAL_AS(p) ((const __attribute__((address_space(1))) void*)(p))
#define LDS_AS(p)    ((__attribute__((address_space(3))) void*)(p))

#define LOG2E 1.4426950408889634f

// ---------------------------------------------------------------------------
// fused prep: blocks [0,4096) convert x fp32->fp16; [4096,4864) transpose
// Wqkv [1024,3072] -> WTh [3072,1024]; [4864,5120) transpose Wp -> WpT.
// ---------------------------------------------------------------------------
__global__ __launch_bounds__(256) void prep(
    const float* __restrict__ x, const float* __restrict__ Wqkv,
    const float* __restrict__ Wp,
    _Float16* __restrict__ xh, _Float16* __restrict__ WTh,
    _Float16* __restrict__ WpT)
{
    const int bid = blockIdx.x;
    if (bid < 4096) {
        const int i = bid * 256 + threadIdx.x;
        const float4_t v = ((const float4_t*)x)[i];
        half4 hh;
#pragma unroll
        for (int j = 0; j < 4; ++j) hh[j] = (_Float16)v[j];
        ((half4*)xh)[i] = hh;
        return;
    }
    __shared__ float t[64][65];
    const float* in;
    _Float16* out;
    int R, C, bx, by;
    if (bid < 4096 + 768) {
        const int idx = bid - 4096;
        bx = idx % 48; by = idx / 48;
        in = Wqkv; out = WTh; R = 1024; C = 3072;
    } else {
        const int idx = bid - 4864;
        bx = idx & 15; by = idx >> 4;
        in = Wp; out = WpT; R = 1024; C = 1024;
    }
    const int r0 = by * 64, c0 = bx * 64;
    for (int i = threadIdx.x; i < 64 * 64; i += 256) {
        int r = i >> 6, c = i & 63;
        t[r][c] = in[(size_t)(r0 + r) * C + c0 + c];
    }
    __syncthreads();
    for (int i = threadIdx.x; i < 64 * 64; i += 256) {
        int c = i >> 6, r = i & 63;
        out[(size_t)(c0 + c) * R + r0 + r] = (_Float16)t[r][c];
    }
}

// ---------------------------------------------------------------------------
// QKV GEMM, plain fp16, m97 structure: 128x128 tile, BK=32, global_load_lds.
// Epilogue: cols<1024 -> q plane; 1024..2047 -> k plane SCALED by log2(e);
// cols>=2048 -> fp16 V^T [1024,4096], packed half4 along s.
// ---------------------------------------------------------------------------
__global__ __launch_bounds__(256) void gemm_qkv(
    const _Float16* __restrict__ Ag, const _Float16* __restrict__ Bg,
    const float* __restrict__ bias,
    _Float16* __restrict__ qk, _Float16* __restrict__ vt, int K)
{
    constexpr int BK = 32;
    __shared__ _Float16 Ah[128 * BK];
    __shared__ _Float16 Bh[128 * BK];

    const int tid = threadIdx.x;
    const int wave = tid >> 6, lane = tid & 63;
    const int l16 = lane & 15, quad = lane >> 4;
    const int wr = wave >> 1, wc = wave & 1;
    const int row0 = blockIdx.y * 128, col0 = blockIdx.x * 128;
    const int lrow = lane >> 2, lc8 = (lane & 3) * 8;

    float4_t acc[4][4];
#pragma unroll
    for (int i = 0; i < 4; ++i)
#pragma unroll
        for (int j = 0; j < 4; ++j) acc[i][j] = (float4_t){0.f, 0.f, 0.f, 0.f};

    for (int k0 = 0; k0 < K; k0 += BK) {
        __syncthreads();
#pragma unroll
        for (int i = 0; i < 2; ++i) {
            const int ar = i * 64 + wave * 16;
            __builtin_amdgcn_global_load_lds(
                GLOBAL_AS(Ag + (size_t)(row0 + ar + lrow) * K + k0 + lc8),
                LDS_AS(&Ah[ar * BK]), 16, 0, 0);
            __builtin_amdgcn_global_load_lds(
                GLOBAL_AS(Bg + (size_t)(col0 + ar + lrow) * K + k0 + lc8),
                LDS_AS(&Bh[ar * BK]), 16, 0, 0);
        }
        __syncthreads();

        half8 af[4], bfr[4];
#pragma unroll
        for (int t = 0; t < 4; ++t) {
            af[t]  = *(const half8*)&Ah[(wr * 64 + t * 16 + l16) * BK + quad * 8];
            bfr[t] = *(const half8*)&Bh[(wc * 64 + t * 16 + l16) * BK + quad * 8];
        }
#pragma unroll
        for (int i = 0; i < 4; ++i)
#pragma unroll
            for (int j = 0; j < 4; ++j)
                acc[i][j] = __builtin_amdgcn_mfma_f32_16x16x32_f16(af[i], bfr[j], acc[i][j], 0, 0, 0);
    }

#pragma unroll
    for (int i = 0; i < 4; ++i) {
#pragma unroll
        for (int j = 0; j < 4; ++j) {
            const int colb = col0 + wc * 64 + j * 16 + l16;
            const float bv = bias[colb];
            const int rowb = row0 + wr * 64 + i * 16 + quad * 4;
            if (colb < 2048) {
                const float sc = (colb >= 1024) ? LOG2E : 1.0f;
#pragma unroll
                for (int r = 0; r < 4; ++r)
                    qk[(size_t)(rowb + r) * 2048 + colb] =
                        (_Float16)((acc[i][j][r] + bv) * sc);
            } else {
                half4 w;
#pragma unroll
                for (int r = 0; r < 4; ++r) w[r] = (_Float16)(acc[i][j][r] + bv);
                *(half4*)&vt[(size_t)(colb - 2048) * 4096 + rowb] = w;
            }
        }
    }
}

// ---------------------------------------------------------------------------
// Out-projection GEMM, fp16, 128(M)x64(N) tile -> 512 blocks (2/CU; was 256
// = 1/CU latency-bound). 4 waves: wave owns 32 M-rows x full 64 N.
// ---------------------------------------------------------------------------
__global__ __launch_bounds__(256) void gemm_out(
    const _Float16* __restrict__ Ag, const _Float16* __restrict__ Bg,
    const float* __restrict__ bias, float* __restrict__ C, int N, int K)
{
    constexpr int BK = 32;
    __shared__ _Float16 Ah[128 * BK];
    __shared__ _Float16 Bh[64 * BK];

    const int tid = threadIdx.x;
    const int wave = tid >> 6, lane = tid & 63;
    const int l16 = lane & 15, quad = lane >> 4;
    const int row0 = blockIdx.y * 128, col0 = blockIdx.x * 64;
    const int lrow = lane >> 2, lc8 = (lane & 3) * 8;

    float4_t acc[2][4];
#pragma unroll
    for (int i = 0; i < 2; ++i)
#pragma unroll
        for (int j = 0; j < 4; ++j) acc[i][j] = (float4_t){0.f, 0.f, 0.f, 0.f};

    for (int k0 = 0; k0 < K; k0 += BK) {
        __syncthreads();
#pragma unroll
        for (int i = 0; i < 2; ++i) {
            const int ar = i * 64 + wave * 16;
            __builtin_amdgcn_global_load_lds(
                GLOBAL_AS(Ag + (size_t)(row0 + ar + lrow) * K + k0 + lc8),
                LDS_AS(&Ah[ar * BK]), 16, 0, 0);
        }
        {
            const int br = wave * 16;
            __builtin_amdgcn_global_load_lds(
                GLOBAL_AS(Bg + (size_t)(col0 + br + lrow) * K + k0 + lc8),
                LDS_AS(&Bh[br * BK]), 16, 0, 0);
        }
        __syncthreads();

        half8 af[2], bfr[4];
#pragma unroll
        for (int t = 0; t < 2; ++t)
            af[t] = *(const half8*)&Ah[(wave * 32 + t * 16 + l16) * BK + quad * 8];
#pragma unroll
        for (int t = 0; t < 4; ++t)
            bfr[t] = *(const half8*)&Bh[(t * 16 + l16) * BK + quad * 8];
#pragma unroll
        for (int i = 0; i < 2; ++i)
#pragma unroll
            for (int j = 0; j < 4; ++j)
                acc[i][j] = __builtin_amdgcn_mfma_f32_16x16x32_f16(af[i], bfr[j], acc[i][j], 0, 0, 0);
    }

#pragma unroll
    for (int i = 0; i < 2; ++i) {
#pragma unroll
        for (int j = 0; j < 4; ++j) {
            const int colb = col0 + j * 16 + l16;
            const float bv = bias[colb];
#pragma unroll
            for (int r = 0; r < 4; ++r) {
                const int row = row0 + wave * 32 + i * 16 + quad * 4 + r;
                C[(size_t)row * N + colb] = acc[i][j][r] + bv;
            }
        }
    }
}

// ---------------------------------------------------------------------------
// MFMA causal flash attention — round-8 shared-tile structure + DMA staging.
// 1024 blocks x 128 threads (2 waves). Block: tiles {pair, 127-pair} of head
// h = (bid&7)*2 + ((bid>>3)&1) (XCD-pinned K/V in L2); uniform ~65 k-iters.
// K [key][d] and V^T [d][key] tiles (64x64 fp16, unpadded) staged via
// global_load_lds DMA into DOUBLE-BUFFERED LDS with an XOR swizzle applied by
// permuting SOURCE addresses (DMA destination must stay lane-contiguous):
//   physical slot(row, col8) = row*8 + (col8 ^ (row & 7)), 16 B per slot.
// Fragment reads at row = t*16+l16, col8 = quad / quad+4 are then
// conflict-free (each 8-lane phase covers 8 distinct 4-bank groups).
// ONE __syncthreads per k-iter: barrier; DMA(next -> buf^1); compute(buf).
// The barrier's vmcnt(0) only drains a DMA issued a full iteration earlier.
// S^T = K Q^T formulation (round 8): per-lane softmax + 2 shuffles; P via
// per-wave Pb (stride 76: ~2-way banks), 4x b64 write + 2x b128 read.
// ---------------------------------------------------------------------------
__global__ __launch_bounds__(128, 2) void flash_attn_f16(
    const _Float16* __restrict__ qk, const _Float16* __restrict__ v_t,
    _Float16* __restrict__ resh)
{
    __shared__ __align__(16) _Float16 KsT[2][64 * 64];   // [buf][slot*8]
    __shared__ __align__(16) _Float16 VtT[2][64 * 64];
    __shared__ __align__(16) _Float16 Pb[2][16][76];     // per-wave P [q][key]

    const int bid  = blockIdx.x;
    const int h    = (bid & 7) * 2 + ((bid >> 3) & 1);
    const int pair = bid >> 4;                 // 0..63
    const int wave = threadIdx.x >> 6;
    const int lane = threadIdx.x & 63;
    const int l16  = lane & 15;
    const int quad = lane >> 4;

    // DMA source-address components (lane's LDS slot is wave*256+p*64+lane):
    const int dma_r = wave * 32 + (lane >> 3);             // row  (+ p*8)
    const int dma_c = ((lane & 7) ^ (lane >> 3)) * 8;      // logical col (halfs)

    const _Float16* kplane = qk + 1024 + h * HDIM;
    const _Float16* vplane = v_t + (size_t)h * HDIM * 4096;

    for (int hf = 0; hf < 2; ++hf) {
        const int tile = hf ? 127 - pair : pair;
        const int q0   = tile * 32 + wave * 16;
        const int kb_last = (tile >> 1) * 64;

        // ---- Q fragment (B-operand) ---------------------------------------
        const size_t qoff = (size_t)(q0 + l16) * 2048 + h * HDIM + quad * 8;
        half8 qf0 = *(const half8*)(qk + qoff);
        half8 qf1 = *(const half8*)(qk + qoff + 32);

        float4_t o[4];
#pragma unroll
        for (int c = 0; c < 4; ++c) o[c] = (float4_t){0.f, 0.f, 0.f, 0.f};
        float m_r = -INFINITY, l_r = 0.f;

        // ---- pre-stage tile kb=0 into buf 0 (protect from prev readers) ---
        __syncthreads();
#pragma unroll
        for (int p = 0; p < 4; ++p) {
            const int r = dma_r + p * 8;
            __builtin_amdgcn_global_load_lds(
                GLOBAL_AS(kplane + (size_t)r * 2048 + dma_c),
                LDS_AS(&KsT[0][(wave * 256 + p * 64) * 8]), 16, 0, 0);
            __builtin_amdgcn_global_load_lds(
                GLOBAL_AS(vplane + (size_t)r * 4096 + dma_c),
                LDS_AS(&VtT[0][(wave * 256 + p * 64) * 8]), 16, 0, 0);
        }

        int ib = 0;
        for (int kb = 0; kb <= kb_last; kb += 64, ib ^= 1) {
            __syncthreads();   // DMA(buf ib) done (vmcnt drain) + readers done

            if (kb < kb_last) {   // async DMA of next tile into the other buf
                const int kn = kb + 64;
#pragma unroll
                for (int p = 0; p < 4; ++p) {
                    const int r = dma_r + p * 8;
                    __builtin_amdgcn_global_load_lds(
                        GLOBAL_AS(kplane + (size_t)(kn + r) * 2048 + dma_c),
                        LDS_AS(&KsT[ib ^ 1][(wave * 256 + p * 64) * 8]), 16, 0, 0);
                    __builtin_amdgcn_global_load_lds(
                        GLOBAL_AS(vplane + (size_t)r * 4096 + kn + dma_c),
                        LDS_AS(&VtT[ib ^ 1][(wave * 256 + p * 64) * 8]), 16, 0, 0);
                }
            }

            // ---- S^T = K Q^T (log2-domain logits) -------------------------
            float4_t s[4];
#pragma unroll
            for (int t = 0; t < 4; ++t) {
                const int row = t * 16 + l16;
                const int r7 = row & 7;
                half8 a0 = *(const half8*)&KsT[ib][(row * 8 + (quad ^ r7)) * 8];
                half8 a1 = *(const half8*)&KsT[ib][(row * 8 + ((quad + 4) ^ r7)) * 8];
                float4_t a = (float4_t){0.f, 0.f, 0.f, 0.f};
                a = __builtin_amdgcn_mfma_f32_16x16x32_f16(a0, qf0, a, 0, 0, 0);
                a = __builtin_amdgcn_mfma_f32_16x16x32_f16(a1, qf1, a, 0, 0, 0);
                s[t] = a;
            }

            // ---- causal mask (diagonal-straddling tile only) --------------
            if (kb + 63 > q0) {
                const int qg = q0 + l16;
#pragma unroll
                for (int t = 0; t < 4; ++t)
#pragma unroll
                    for (int r = 0; r < 4; ++r) {
                        const int key = kb + t * 16 + quad * 4 + r;
                        if (key > qg) s[t][r] = -INFINITY;
                    }
            }

            // ---- online softmax: per-lane local + 2 cross-quad shuffles ---
            float mx = s[0][0];
#pragma unroll
            for (int t = 0; t < 4; ++t)
#pragma unroll
                for (int r = 0; r < 4; ++r) mx = fmaxf(mx, s[t][r]);
            mx = fmaxf(mx, __shfl_xor(mx, 16));
            mx = fmaxf(mx, __shfl_xor(mx, 32));
            const float mnew  = fmaxf(m_r, mx);
            const float alpha = __builtin_amdgcn_exp2f(m_r - mnew);

            float p[4][4];
            float sum = 0.f;
#pragma unroll
            for (int t = 0; t < 4; ++t)
#pragma unroll
                for (int r = 0; r < 4; ++r) {
                    p[t][r] = __builtin_amdgcn_exp2f(s[t][r] - mnew);
                    sum += p[t][r];
                }
            sum += __shfl_xor(sum, 16);
            sum += __shfl_xor(sum, 32);
            l_r = l_r * alpha + sum;
            m_r = mnew;
#pragma unroll
            for (int ct = 0; ct < 4; ++ct)
#pragma unroll
                for (int r = 0; r < 4; ++r) o[ct][r] *= alpha;

            // ---- P store (4 keys contiguous) + read-back as B-operand -----
#pragma unroll
            for (int t = 0; t < 4; ++t) {
                half4 w;
#pragma unroll
                for (int r = 0; r < 4; ++r) w[r] = (_Float16)p[t][r];
                *(half4*)&Pb[wave][l16][t * 16 + quad * 4] = w;
            }
            half8 pb0 = *(const half8*)&Pb[wave][l16][quad * 8];
            half8 pb1 = *(const half8*)&Pb[wave][l16][32 + quad * 8];

            // ---- O^T += V^T P^T -------------------------------------------
#pragma unroll
            for (int ct = 0; ct < 4; ++ct) {
                const int row = ct * 16 + l16;
                const int r7 = row & 7;
                half8 va0 = *(const half8*)&VtT[ib][(row * 8 + (quad ^ r7)) * 8];
                half8 va1 = *(const half8*)&VtT[ib][(row * 8 + ((quad + 4) ^ r7)) * 8];
                o[ct] = __builtin_amdgcn_mfma_f32_16x16x32_f16(va0, pb0, o[ct], 0, 0, 0);
                o[ct] = __builtin_amdgcn_mfma_f32_16x16x32_f16(va1, pb1, o[ct], 0, 0, 0);
            }
        } // kb

        // ---- epilogue: O^T[d][q] / l -> resh[q][d], half4 packed ----------
        const float inv = 1.0f / l_r;
#pragma unroll
        for (int ct = 0; ct < 4; ++ct) {
            half4 w;
#pragma unroll
            for (int r = 0; r < 4; ++r) w[r] = (_Float16)(o[ct][r] * inv);
            *(half4*)&resh[(size_t)(q0 + l16) * EMB + h * HDIM + ct * 16 + quad * 4] = w;
        }
    } // hf
}

// ---------------------------------------------------------------------------
// launch
// ---------------------------------------------------------------------------
extern "C" void kernel_launch(void* const* d_in, const int* in_sizes, int n_in,
                              void* d_out, int out_size, void* d_ws, size_t ws_size,
                              hipStream_t stream)
{
    const float* x    = (const float*)d_in[0];
    const float* Wqkv = (const float*)d_in[2];
    const float* bqkv = (const float*)d_in[3];
    const float* Wp   = (const float*)d_in[4];
    const float* bp   = (const float*)d_in[5];
    float* out = (float*)d_out;

    _Float16* xh  = (_Float16*)d_ws;                 // [4096,1024] fp16
    _Float16* WTh = xh + (size_t)4096 * 1024;        // [3072,1024] fp16
    _Float16* qkh = WTh + (size_t)3072 * 1024;       // [4096,2048] fp16
    _Float16* vtg = qkh + (size_t)4096 * 2048;       // V^T [1024,4096] fp16
    _Float16* WpT = vtg + (size_t)1024 * 4096;       // [1024,1024] fp16
    _Float16* resh = xh;            // alias: x fp16 dead after QKV GEMM

    dim3 blk(256);

    prep<<<dim3(5120), blk, 0, stream>>>(x, Wqkv, Wp, xh, WTh, WpT);

    gemm_qkv<<<dim3(3072 / 128, 4096 / 128), blk, 0, stream>>>(
        xh, WTh, bqkv, qkh, vtg, 1024);

    flash_attn_f16<<<dim3(1024), dim3(128), 0, stream>>>(qkh, vtg, resh);

    gemm_out<<<dim3(1024 / 64, 4096 / 128), blk, 0, stream>>>(
        resh, WpT, bp, out, 1024, 1024);
}